// Round 7
// baseline (320.917 us; speedup 1.0000x reference)
//
#include <hip/hip_runtime.h>
#include <stdint.h>

#define NUM_CLASSES 80
#define N_ANCH 25200
#define B_IMG 16
#define NMS_TOPK_ 128
#define MAX_OUT_ 100
#define SCORE_THR_ 0.25f
#define IOU_THR_ 0.45f
#define NBINS 2048      // fallback/final histogram bins
#define CAP 2048        // fallback path capacity
#define CAPB 1024       // u8-select candidate capacity
#define CAPC 256        // stage-C capacity
#define U8_BASE 0x3E7Eu // 2-ulp margin below u16(0.25)=0x3E80 (screening only)
#define TILES_PER_IMG 394   // p3:300 + p4:75 + p5:19 (last p5 tile = 48 anchors)

__constant__ float c_anch[9][2] = {
    {10.f, 13.f}, {16.f, 30.f}, {33.f, 23.f},
    {30.f, 61.f}, {62.f, 45.f}, {59.f, 119.f},
    {116.f, 90.f}, {156.f, 198.f}, {373.f, 326.f}};

// Exact sigmoid — used for box decode and exact re-scoring (must match jax).
__device__ __forceinline__ float sigmoidf_(float x) {
    return 1.0f / (1.0f + expf(-x));
}

// Fast screening sigmoid. ONLY feeds the u8 screening tensor.
__device__ __forceinline__ float fast_sigmoid_(float x) {
    float t = __expf(-x);
    return __fdividef(1.0f, 1.0f + t);
}

// Map score to u8 screening bin. 0 = below ~0.2485 (margin), 1..255 above.
__device__ __forceinline__ unsigned int score_u8_(float s) {
    unsigned int u = __float_as_uint(s) >> 16;
    int bin = (int)u - (int)U8_BASE;
    if (bin < 0) bin = 0;
    if (bin > 255) bin = 255;
    return (unsigned int)bin;
}

__device__ __forceinline__ unsigned int score_bin(unsigned int bits) {
    // fallback/final: scores in (0.25, 1.0): bits in (0x3E800000, 0x3F800000)
    unsigned int bin = (bits - 0x3E800000u) >> 13;
    if (bin >= NBINS) bin = NBINS - 1;
    return bin;
}

// Exact on-the-fly box decode (same formula/order as reference).
__device__ __forceinline__ float4 decode_box_(
    const float* __restrict__ p3, const float* __restrict__ p4,
    const float* __restrict__ p5, int b, unsigned int idx) {
    const float* p; int W, lvl, il;
    if (idx < 19200u)      { p = p3; W = 80; lvl = 0; il = (int)idx; }
    else if (idx < 24000u) { p = p4; W = 40; lvl = 1; il = (int)idx - 19200; }
    else                   { p = p5; W = 20; lvl = 2; il = (int)idx - 24000; }
    float stride = (float)(8 << lvl);
    int y = il / (W * 3);
    int t = il - y * (W * 3);
    int x = t / 3;
    int a = t - x * 3;
    const float* q = p + (size_t)b * ((size_t)W * W * 255) + (size_t)il * 85;
    float cx = (sigmoidf_(q[0]) + (float)x) * stride;
    float cy = (sigmoidf_(q[1]) + (float)y) * stride;
    float bw = expf(q[2]) * c_anch[lvl * 3 + a][0];
    float bh = expf(q[3]) * c_anch[lvl * 3 + a][1];
    return make_float4(cx - bw * 0.5f, cy - bh * 0.5f,
                       cx + bw * 0.5f, cy + bh * 0.5f);
}

#define WRED_(r) { r += __shfl_xor(r, 1); r += __shfl_xor(r, 2); \
                   r += __shfl_xor(r, 4); r += __shfl_xor(r, 8); \
                   r += __shfl_xor(r, 16); r += __shfl_xor(r, 32); }

// ============================================================================
// FAST PATH
// ============================================================================

// ---- F1: score-only decode. Block = 64-anchor tile; lane = anchor; wave w
// covers classes 20w..20w+19. No box math (NMS decodes boxes lazily).
__global__ void __launch_bounds__(256) decode_score_kernel(
    const float* __restrict__ p3, const float* __restrict__ p4,
    const float* __restrict__ p5, unsigned char* __restrict__ score_u8) {
    int blk = blockIdx.x;
    int b = blk / TILES_PER_IMG;
    int tile = blk - b * TILES_PER_IMG;
    const float* p; int W, il0, base, ta;
    if (tile < 300)      { p = p3; W = 80; il0 = tile * 64;         base = 0;     ta = 64; }
    else if (tile < 375) { p = p4; W = 40; il0 = (tile - 300) * 64; base = 19200; ta = 64; }
    else                 { p = p5; W = 20; il0 = (tile - 375) * 64; base = 24000;
                           ta = (tile == 393) ? 48 : 64; }

    __shared__ float raw[64 * 85];   // 21760 B
    int tid = threadIdx.x;

    {
        const float4* src4 = (const float4*)(p + (size_t)b * ((size_t)W * W * 255) +
                                             (size_t)il0 * 85);
        float4* raw4 = (float4*)raw;
        int n4 = ta * 85 / 4;   // 1360 or 1020
        for (int k = tid; k < n4; k += 256) raw4[k] = src4[k];
    }
    __syncthreads();

    int wave = tid >> 6;
    int lane = tid & 63;

    if (lane < ta) {
        const float* q = &raw[lane * 85];
        float obj = fast_sigmoid_(q[4]);          // register; screening only
        size_t sb = (size_t)b * NUM_CLASSES * N_ANCH + (size_t)(base + il0 + lane);
#pragma unroll
        for (int it = 0; it < 20; ++it) {
            int c = wave * 20 + it;
            float s = obj * fast_sigmoid_(q[5 + c]);
            score_u8[sb + (size_t)c * N_ANCH] = (unsigned char)score_u8_(s);
        }
    }
}

// ---- F2a: per (image,class) top-128 selection over u8 screening bins.
// Coarse 8-range register pre-count -> 32-bin bracket -> fine histogram of
// bracket only (atomics ~250 instead of ~10,500). Cutoff value identical to
// the full-histogram algorithm; -1 margin collect; exact rescore; sort.
__global__ void __launch_bounds__(256) select_topk_u8_kernel(
    const unsigned char* __restrict__ score_u8,
    const float* __restrict__ p3, const float* __restrict__ p4,
    const float* __restrict__ p5,
    unsigned long long* __restrict__ topsel) {
    int bc = blockIdx.x;
    int b = bc / NUM_CLASSES;
    int c = bc - b * NUM_CLASSES;
    int tid = threadIdx.x;
    int wave = tid >> 6;
    int lane = tid & 63;
    const uint4* sc = (const uint4*)(score_u8 + (size_t)bc * N_ANCH);

    __shared__ unsigned int rng[8];               // coarse range counts
    __shared__ unsigned int hist[4][256];         // fine, per-wave copies
    __shared__ unsigned long long sel[CAPB];      // 8 KB
    __shared__ unsigned int s_cnt, s_base;
    __shared__ int s_cut, s_lo, s_hi;

    if (tid < 8) rng[tid] = 0u;
#pragma unroll
    for (int wv = 0; wv < 4; ++wv) hist[wv][tid & 255] = 0u;
    if (tid == 0) s_cnt = 0u;
    __syncthreads();

    // Pass 0: coarse counts in registers (balanced compare tree, no atomics)
    {
        unsigned int r0 = 0, r1 = 0, r2 = 0, r3 = 0, r4 = 0, r5 = 0, r6 = 0, r7 = 0;
        for (int i = tid; i < N_ANCH / 16; i += 256) {
            uint4 v = sc[i];
            unsigned int ww[4] = {v.x, v.y, v.z, v.w};
#pragma unroll
            for (int k = 0; k < 16; ++k) {
                unsigned int b8 = (ww[k >> 2] >> ((k & 3) * 8)) & 0xFFu;
                if (b8 >= 128u) {
                    if (b8 >= 192u) { if (b8 >= 224u) ++r7; else ++r6; }
                    else            { if (b8 >= 160u) ++r5; else ++r4; }
                } else if (b8) {
                    if (b8 >= 64u)  { if (b8 >= 96u)  ++r3; else ++r2; }
                    else            { if (b8 >= 32u)  ++r1; else ++r0; }
                }
            }
        }
        WRED_(r0) WRED_(r1) WRED_(r2) WRED_(r3)
        WRED_(r4) WRED_(r5) WRED_(r6) WRED_(r7)
        if (lane == 0) {
            atomicAdd(&rng[0], r0); atomicAdd(&rng[1], r1);
            atomicAdd(&rng[2], r2); atomicAdd(&rng[3], r3);
            atomicAdd(&rng[4], r4); atomicAdd(&rng[5], r5);
            atomicAdd(&rng[6], r6); atomicAdd(&rng[7], r7);
        }
    }
    __syncthreads();

    // Bracket the 128th rank: range j = [lo, hi) with cum(>=hi) < 128 <= cum(>=lo)
    if (tid == 0) {
        unsigned int cum = 0; int j = -1;
        for (int k = 7; k >= 0; --k) {
            cum += rng[k];
            if (cum >= NMS_TOPK_) { j = k; break; }
        }
        if (j < 0) {
            s_cut = 1; s_lo = 256; s_hi = 256; s_base = 0u;  // <128 nonzero total
        } else {
            s_lo = (j == 0) ? 1 : (32 * j);
            s_hi = 32 * (j + 1);
            s_base = cum - rng[j];   // count of bins >= s_hi
            s_cut = (j == 0) ? 1 : (32 * j);  // default (overwritten below)
        }
    }
    __syncthreads();

    if (s_lo < 256) {
        int lo = s_lo, hi = s_hi;
        // Fine pass: histogram ONLY bracket elements
        unsigned int* myhist = hist[wave];
        for (int i = tid; i < N_ANCH / 16; i += 256) {
            uint4 v = sc[i];
            unsigned int ww[4] = {v.x, v.y, v.z, v.w};
#pragma unroll
            for (int k = 0; k < 16; ++k) {
                int bin = (int)((ww[k >> 2] >> ((k & 3) * 8)) & 0xFFu);
                if (bin >= lo && bin < hi) atomicAdd(&myhist[bin], 1u);
            }
        }
        __syncthreads();
        {
            unsigned int m = hist[0][tid] + hist[1][tid] + hist[2][tid] + hist[3][tid];
            hist[0][tid] = m;
        }
        __syncthreads();
        if (tid == 0) {
            unsigned int tot = s_base; int cut = s_lo;
            for (int t = s_hi - 1; t >= s_lo; --t) {
                tot += hist[0][t];
                if (tot >= NMS_TOPK_) { cut = t; break; }
            }
            s_cut = cut;
        }
        __syncthreads();
    }
    int coll = s_cut - 1;     // -1 margin: fast-vs-exact error << 1 bin
    if (coll < 1) coll = 1;

    // Pass 2: collect candidate indices at/above collection bin
    for (int i = tid; i < N_ANCH / 16; i += 256) {
        uint4 v = sc[i];
        unsigned int ww[4] = {v.x, v.y, v.z, v.w};
#pragma unroll
        for (int k = 0; k < 16; ++k) {
            int bin = (int)((ww[k >> 2] >> ((k & 3) * 8)) & 0xFFu);
            if (bin >= coll) {
                unsigned int pos = atomicAdd(&s_cnt, 1u);
                if (pos < CAPB) sel[pos] = (unsigned long long)(i * 16 + k);
            }
        }
    }
    __syncthreads();

    unsigned int M = s_cnt;
    if (M > CAPB) M = CAPB;

    // EXACT score recompute (bitwise identical formula to reference)
    for (unsigned int t = tid; t < M; t += 256) {
        unsigned int idx = (unsigned int)sel[t];
        const float* q;
        if (idx < 19200u)      q = p3 + (size_t)b * 1632000 + (size_t)idx * 85;
        else if (idx < 24000u) q = p4 + (size_t)b * 408000 + (size_t)(idx - 19200u) * 85;
        else                   q = p5 + (size_t)b * 102000 + (size_t)(idx - 24000u) * 85;
        float s = sigmoidf_(q[4]) * sigmoidf_(q[5 + c]);
        sel[t] = (s > SCORE_THR_)
                     ? (((unsigned long long)__float_as_uint(s) << 32) |
                        (unsigned long long)(~idx))
                     : 0ull;
    }
    __syncthreads();

    unsigned int P2 = 1;
    while (P2 < M) P2 <<= 1;
    if (P2 < 2) P2 = 2;
    for (unsigned int k = M + tid; k < P2; k += 256) sel[k] = 0ull;
    __syncthreads();

    // 256-thread bitonic sort, desc order
    for (unsigned int k = 2; k <= P2; k <<= 1) {
        for (unsigned int j = k >> 1; j > 0; j >>= 1) {
            for (unsigned int t = tid; t < (int)P2; t += 256) {
                unsigned int ixj = (unsigned int)t ^ j;
                if (ixj > (unsigned int)t) {
                    unsigned long long a0 = sel[t], b0 = sel[ixj];
                    bool desc = (((unsigned int)t & k) == 0);
                    if (desc ? (a0 < b0) : (a0 > b0)) { sel[t] = b0; sel[ixj] = a0; }
                }
            }
            __syncthreads();
        }
    }

    unsigned long long* dst = topsel + (size_t)bc * NMS_TOPK_;
    if (tid < NMS_TOPK_) dst[tid] = ((unsigned int)tid < M) ? sel[tid] : 0ull;
}

// ---- F2b: wave-synchronous greedy NMS; boxes decoded on-the-fly (exact) ----
__global__ void __launch_bounds__(64) nms_kernel(
    const unsigned long long* __restrict__ topsel,
    const float* __restrict__ p3, const float* __restrict__ p4,
    const float* __restrict__ p5,
    float* __restrict__ cls_score, float* __restrict__ cls_box) {
    int bc = blockIdx.x;
    int b = bc / NUM_CLASSES;
    unsigned int lane = threadIdx.x;

    __shared__ float bx[NMS_TOPK_][8];   // box(4) + pad; float4-aligned rows

    const unsigned long long* src = topsel + (size_t)bc * NMS_TOPK_;
    unsigned long long e0 = src[lane];
    unsigned long long e1 = src[64 + lane];

    bool k0 = (e0 != 0ull);
    bool k1 = (e1 != 0ull);

    float x00 = 0, y00 = 0, x01 = 0, y01 = 0, a0 = 0, sv0 = 0;
    float x10 = 0, y10 = 0, x11 = 0, y11 = 0, a1 = 0, sv1 = 0;
    if (k0) {
        unsigned int idx = ~((unsigned int)(e0 & 0xFFFFFFFFull));
        float4 bp = decode_box_(p3, p4, p5, b, idx);
        x00 = bp.x; y00 = bp.y; x01 = bp.z; y01 = bp.w;
        sv0 = __uint_as_float((unsigned int)(e0 >> 32));
        a0 = (x01 - x00) * (y01 - y00);
    }
    if (k1) {
        unsigned int idx = ~((unsigned int)(e1 & 0xFFFFFFFFull));
        float4 bp = decode_box_(p3, p4, p5, b, idx);
        x10 = bp.x; y10 = bp.y; x11 = bp.z; y11 = bp.w;
        sv1 = __uint_as_float((unsigned int)(e1 >> 32));
        a1 = (x11 - x10) * (y11 - y10);
    }
    {
        float4 v0 = {x00, y00, x01, y01};
        float4 v1 = {x10, y10, x11, y11};
        *(float4*)&bx[lane][0] = v0;
        *(float4*)&bx[64 + lane][0] = v1;
    }
    __syncthreads();

    unsigned long long km0 = __ballot(k0);
    unsigned long long km1 = __ballot(k1);
    for (unsigned int i = 0; i < NMS_TOPK_; ++i) {
        bool ki = ((((i < 64) ? km0 : km1) >> (i & 63)) & 1ull) != 0ull;
        if (ki) {
            float4 rb = *(const float4*)&bx[i][0];
            float ra = (rb.z - rb.x) * (rb.w - rb.y);
            if (k0 && lane > i) {
                float lx = fmaxf(rb.x, x00), ly = fmaxf(rb.y, y00);
                float rx = fminf(rb.z, x01), ry = fminf(rb.w, y01);
                float w = fmaxf(rx - lx, 0.f), h = fmaxf(ry - ly, 0.f);
                float inter = w * h;
                float iou = inter / (ra + a0 - inter + 1e-9f);
                if (iou > IOU_THR_) k0 = false;
            }
            if (k1 && (64 + lane) > i) {
                float lx = fmaxf(rb.x, x10), ly = fmaxf(rb.y, y10);
                float rx = fminf(rb.z, x11), ry = fminf(rb.w, y11);
                float w = fmaxf(rx - lx, 0.f), h = fmaxf(ry - ly, 0.f);
                float inter = w * h;
                float iou = inter / (ra + a1 - inter + 1e-9f);
                if (iou > IOU_THR_) k1 = false;
            }
            km0 = __ballot(k0);
            km1 = __ballot(k1);
        }
    }

    float* scd = cls_score + (size_t)bc * MAX_OUT_;
    float* bod = cls_box + (size_t)bc * (MAX_OUT_ * 4);
    int n0 = __popcll(km0);
    int n = n0 + __popcll(km1);
    if (k0) {
        int pos = __popcll(km0 & ((1ull << lane) - 1ull));
        if (pos < MAX_OUT_) {
            scd[pos] = sv0;
            bod[pos * 4 + 0] = x00; bod[pos * 4 + 1] = y00;
            bod[pos * 4 + 2] = x01; bod[pos * 4 + 3] = y01;
        }
    }
    if (k1) {
        int pos = n0 + __popcll(km1 & ((1ull << lane) - 1ull));
        if (pos < MAX_OUT_) {
            scd[pos] = sv1;
            bod[pos * 4 + 0] = x10; bod[pos * 4 + 1] = y10;
            bod[pos * 4 + 2] = x11; bod[pos * 4 + 3] = y11;
        }
    }
    int start = n < MAX_OUT_ ? n : MAX_OUT_;
    for (int p2 = start + (int)lane; p2 < MAX_OUT_; p2 += 64) {
        scd[p2] = -1.0f;
        bod[p2 * 4 + 0] = 0.f; bod[p2 * 4 + 1] = 0.f;
        bod[p2 * 4 + 2] = 0.f; bod[p2 * 4 + 3] = 0.f;
    }
}

// ---- F3: per-image final top-100; per-wave histogram replication ----
__global__ void __launch_bounds__(256) final_fast_kernel(
    const float* __restrict__ cls_score, const float* __restrict__ cls_box,
    float* __restrict__ out) {
    int b = blockIdx.x;
    int tid = threadIdx.x;
    int wave = tid >> 6;
    const int NC = NUM_CLASSES * MAX_OUT_;  // 8000
    const float* sc = cls_score + (size_t)b * NC;

    __shared__ unsigned int hist[4][NBINS];       // 32 KB, per-wave copies
    __shared__ unsigned int segsum[256];
    __shared__ unsigned long long keys[CAPC];
    __shared__ unsigned int s_cnt, s_tot;
    __shared__ int s_cut;

    for (int k = tid; k < NBINS; k += 256) {
        hist[0][k] = 0u; hist[1][k] = 0u; hist[2][k] = 0u; hist[3][k] = 0u;
    }
    if (tid == 0) s_cnt = 0u;
    __syncthreads();

    unsigned int* myhist = hist[wave];
    for (int k = tid; k < NC; k += 256) {
        float s = sc[k];
        if (s > 0.0f) atomicAdd(&myhist[score_bin(__float_as_uint(s))], 1u);
    }
    __syncthreads();
    for (int k = tid; k < NBINS; k += 256) {
        hist[0][k] = hist[0][k] + hist[1][k] + hist[2][k] + hist[3][k];
    }
    __syncthreads();

    unsigned int ss = 0;
    for (int k = 0; k < 8; ++k) ss += hist[0][tid * 8 + k];
    segsum[tid] = ss;
    __syncthreads();
    if (tid == 0) {
        unsigned int total = 0;
        for (int t = 0; t < 256; ++t) total += segsum[t];
        s_tot = total;
        unsigned int tot = 0; int cut = 0; int t = 255;
        for (; t >= 0; --t) {
            if (tot + segsum[t] >= MAX_OUT_) break;
            tot += segsum[t];
        }
        if (t >= 0) {
            int j = 7;
            for (; j >= 0; --j) { tot += hist[0][t * 8 + j]; if (tot >= MAX_OUT_) break; }
            if (j < 0) j = 0;
            cut = t * 8 + j;
        }
        s_cut = cut;
    }
    __syncthreads();
    unsigned int cutoff = (unsigned int)s_cut;

    for (int k = tid; k < NC; k += 256) {
        float s = sc[k];
        if (s > 0.0f && score_bin(__float_as_uint(s)) >= cutoff) {
            unsigned int pos = atomicAdd(&s_cnt, 1u);
            if (pos < CAPC) {
                keys[pos] = ((unsigned long long)__float_as_uint(s) << 32) |
                            (unsigned long long)(~(unsigned int)k);
            }
        }
    }
    __syncthreads();

    unsigned int M = s_cnt;
    if (M > CAPC) M = CAPC;
    unsigned int P2 = 1;
    while (P2 < M) P2 <<= 1;
    if (P2 < 2) P2 = 2;
    for (unsigned int k = M + tid; k < P2; k += 256) keys[k] = 0ull;
    __syncthreads();

    for (unsigned int k = 2; k <= P2; k <<= 1) {
        for (unsigned int j = k >> 1; j > 0; j >>= 1) {
            for (unsigned int t = (unsigned int)tid; t < P2; t += 256) {
                unsigned int ixj = t ^ j;
                if (ixj > t) {
                    unsigned long long a0 = keys[t], b0 = keys[ixj];
                    bool desc = ((t & k) == 0);
                    if (desc ? (a0 < b0) : (a0 > b0)) { keys[t] = b0; keys[ixj] = a0; }
                }
            }
            __syncthreads();
        }
    }

    float* ob = out;                              // boxes  16*100*4
    float* os = out + B_IMG * MAX_OUT_ * 4;       // scores 16*100
    float* oc = os + B_IMG * MAX_OUT_;            // cls    16*100
    float* on = oc + B_IMG * MAX_OUT_;            // n_valid 16

    unsigned int K = M < MAX_OUT_ ? M : MAX_OUT_;
    if (tid < MAX_OUT_) {
        if ((unsigned int)tid < K) {
            unsigned long long kk = keys[tid];
            unsigned int flat = ~((unsigned int)(kk & 0xFFFFFFFFull));
            float sv = __uint_as_float((unsigned int)(kk >> 32));
            const float* bp = cls_box + ((size_t)b * NC + flat) * 4;
            os[b * MAX_OUT_ + tid] = sv;
            oc[b * MAX_OUT_ + tid] = (float)(flat / MAX_OUT_);
            ob[(b * MAX_OUT_ + tid) * 4 + 0] = bp[0];
            ob[(b * MAX_OUT_ + tid) * 4 + 1] = bp[1];
            ob[(b * MAX_OUT_ + tid) * 4 + 2] = bp[2];
            ob[(b * MAX_OUT_ + tid) * 4 + 3] = bp[3];
        } else {
            os[b * MAX_OUT_ + tid] = 0.0f;
            oc[b * MAX_OUT_ + tid] = 0.0f;
            ob[(b * MAX_OUT_ + tid) * 4 + 0] = 0.0f;
            ob[(b * MAX_OUT_ + tid) * 4 + 1] = 0.0f;
            ob[(b * MAX_OUT_ + tid) * 4 + 2] = 0.0f;
            ob[(b * MAX_OUT_ + tid) * 4 + 3] = 0.0f;
        }
    }
    if (tid == 0) {
        unsigned int nv = s_tot < MAX_OUT_ ? s_tot : MAX_OUT_;
        on[b] = (float)nv;
    }
}

// ============================================================================
// FALLBACK PATH (round-1, known-correct) — used when ws_size is too small
// ============================================================================

__global__ void __launch_bounds__(256) decode_kernel(
    const float* __restrict__ p3, const float* __restrict__ p4,
    const float* __restrict__ p5, float* __restrict__ boxes,
    float* __restrict__ obj) {
    int gid = blockIdx.x * blockDim.x + threadIdx.x;
    if (gid >= B_IMG * N_ANCH) return;
    int b = gid / N_ANCH;
    int i = gid - b * N_ANCH;
    const float* p; int W, il, lvl; float stride;
    if (i < 19200)      { p = p3; W = 80; il = i;         lvl = 0; stride = 8.f;  }
    else if (i < 24000) { p = p4; W = 40; il = i - 19200; lvl = 1; stride = 16.f; }
    else                { p = p5; W = 20; il = i - 24000; lvl = 2; stride = 32.f; }
    int y = il / (W * 3);
    int t = il - y * W * 3;
    int x = t / 3;
    int a = t - x * 3;
    const float* q = p + ((((size_t)b * W + y) * W + x) * 255 + a * 85);
    float cx = (sigmoidf_(q[0]) + (float)x) * stride;
    float cy = (sigmoidf_(q[1]) + (float)y) * stride;
    float bw = expf(q[2]) * c_anch[lvl * 3 + a][0];
    float bh = expf(q[3]) * c_anch[lvl * 3 + a][1];
    float* bo = boxes + (size_t)gid * 4;
    bo[0] = cx - bw * 0.5f; bo[1] = cy - bh * 0.5f;
    bo[2] = cx + bw * 0.5f; bo[3] = cy + bh * 0.5f;
    obj[gid] = sigmoidf_(q[4]);
}

__device__ __forceinline__ float cand_score(
    const float* __restrict__ p3, const float* __restrict__ p4,
    const float* __restrict__ p5, const float* __restrict__ obj,
    int b, int c, int i) {
    const float* p; int W, il;
    if (i < 19200)      { p = p3; W = 80; il = i;         }
    else if (i < 24000) { p = p4; W = 40; il = i - 19200; }
    else                { p = p5; W = 20; il = i - 24000; }
    int y = il / (W * 3);
    int t = il - y * W * 3;
    int x = t / 3;
    int a = t - x * 3;
    float cl = p[(((size_t)b * W + y) * W + x) * 255 + a * 85 + 5 + c];
    return obj[b * N_ANCH + i] * sigmoidf_(cl);
}

__global__ void __launch_bounds__(256) topk_nms_kernel(
    const float* __restrict__ p3, const float* __restrict__ p4,
    const float* __restrict__ p5, const float* __restrict__ boxes,
    const float* __restrict__ obj, float* __restrict__ cls_score,
    float* __restrict__ cls_box) {
    int b = blockIdx.x / NUM_CLASSES;
    int c = blockIdx.x % NUM_CLASSES;
    int tid = threadIdx.x;

    __shared__ unsigned int hist[NBINS];
    __shared__ unsigned long long keys[CAP];
    __shared__ unsigned int s_cnt, s_cutoff;
    __shared__ float bx[NMS_TOPK_][5];
    __shared__ float bs[NMS_TOPK_];
    __shared__ int keep[NMS_TOPK_];

    for (int k = tid; k < NBINS; k += 256) hist[k] = 0u;
    if (tid == 0) s_cnt = 0u;
    __syncthreads();

    for (int i = tid; i < N_ANCH; i += 256) {
        float s = cand_score(p3, p4, p5, obj, b, c, i);
        if (s > SCORE_THR_) atomicAdd(&hist[score_bin(__float_as_uint(s))], 1u);
    }
    __syncthreads();

    if (tid == 0) {
        unsigned int total = 0;
        int cut = 0;
        for (int k = NBINS - 1; k >= 0; --k) {
            total += hist[k];
            if (total >= NMS_TOPK_) { cut = k; break; }
        }
        s_cutoff = (unsigned int)cut;
    }
    __syncthreads();
    unsigned int cutoff = s_cutoff;

    for (int i = tid; i < N_ANCH; i += 256) {
        float s = cand_score(p3, p4, p5, obj, b, c, i);
        if (s > SCORE_THR_) {
            unsigned int bits = __float_as_uint(s);
            if (score_bin(bits) >= cutoff) {
                unsigned int pos = atomicAdd(&s_cnt, 1u);
                if (pos < CAP) {
                    keys[pos] = ((unsigned long long)bits << 32) |
                                (unsigned long long)(~(unsigned int)i);
                }
            }
        }
    }
    __syncthreads();

    unsigned int M = s_cnt;
    if (M > CAP) M = CAP;
    unsigned int P2 = 1;
    while (P2 < M) P2 <<= 1;
    if (P2 < 2) P2 = 2;
    for (unsigned int k = M + tid; k < P2; k += 256) keys[k] = 0ull;
    __syncthreads();

    for (unsigned int k = 2; k <= P2; k <<= 1) {
        for (unsigned int j = k >> 1; j > 0; j >>= 1) {
            for (unsigned int t = tid; t < P2; t += 256) {
                unsigned int ixj = t ^ j;
                if (ixj > t) {
                    unsigned long long a0 = keys[t], b0 = keys[ixj];
                    bool desc = ((t & k) == 0);
                    if (desc ? (a0 < b0) : (a0 > b0)) { keys[t] = b0; keys[ixj] = a0; }
                }
            }
            __syncthreads();
        }
    }

    unsigned int K = M < NMS_TOPK_ ? M : NMS_TOPK_;
    if (tid < (int)K) {
        unsigned long long kk = keys[tid];
        unsigned int idx = ~((unsigned int)(kk & 0xFFFFFFFFull));
        const float* bp = boxes + ((size_t)b * N_ANCH + idx) * 4;
        bx[tid][0] = bp[0]; bx[tid][1] = bp[1];
        bx[tid][2] = bp[2]; bx[tid][3] = bp[3];
        bs[tid] = __uint_as_float((unsigned int)(kk >> 32));
        keep[tid] = 1;
    }
    __syncthreads();

    for (unsigned int i = 0; i < K; ++i) {
        if (keep[i]) {
            unsigned int t = (unsigned int)tid;
            if (t > i && t < K && keep[t]) {
                float ax0 = bx[i][0], ay0 = bx[i][1], ax1 = bx[i][2], ay1 = bx[i][3];
                float cx0 = bx[t][0], cy0 = bx[t][1], cx1 = bx[t][2], cy1 = bx[t][3];
                float areaA = (ax1 - ax0) * (ay1 - ay0);
                float areaB = (cx1 - cx0) * (cy1 - cy0);
                float lx = fmaxf(ax0, cx0), ly = fmaxf(ay0, cy0);
                float rx = fminf(ax1, cx1), ry = fminf(ay1, cy1);
                float w = rx - lx; if (w < 0.f) w = 0.f;
                float h = ry - ly; if (h < 0.f) h = 0.f;
                float inter = w * h;
                float iou = inter / (areaA + areaB - inter + 1e-9f);
                if (iou > IOU_THR_) keep[t] = 0;
            }
        }
        __syncthreads();
    }

    if (tid == 0) {
        float* scd = cls_score + ((size_t)b * NUM_CLASSES + c) * MAX_OUT_;
        float* bod = cls_box + ((size_t)b * NUM_CLASSES + c) * MAX_OUT_ * 4;
        int out_n = 0;
        for (unsigned int t2 = 0; t2 < K && out_n < MAX_OUT_; ++t2) {
            if (keep[t2]) {
                scd[out_n] = bs[t2];
                bod[out_n * 4 + 0] = bx[t2][0];
                bod[out_n * 4 + 1] = bx[t2][1];
                bod[out_n * 4 + 2] = bx[t2][2];
                bod[out_n * 4 + 3] = bx[t2][3];
                out_n++;
            }
        }
        for (; out_n < MAX_OUT_; ++out_n) {
            scd[out_n] = -1.0f;
            bod[out_n * 4 + 0] = 0.f; bod[out_n * 4 + 1] = 0.f;
            bod[out_n * 4 + 2] = 0.f; bod[out_n * 4 + 3] = 0.f;
        }
    }
}

extern "C" void kernel_launch(void* const* d_in, const int* in_sizes, int n_in,
                              void* d_out, int out_size, void* d_ws, size_t ws_size,
                              hipStream_t stream) {
    const float* p3 = (const float*)d_in[0];
    const float* p4 = (const float*)d_in[1];
    const float* p5 = (const float*)d_in[2];

    const size_t clsSB   = (size_t)B_IMG * NUM_CLASSES * MAX_OUT_ * sizeof(float); // 512,000
    const size_t clsBB   = clsSB * 4;                                              // 2,048,000
    const size_t topselB = (size_t)B_IMG * NUM_CLASSES * NMS_TOPK_ * 8;            // 1,310,720
    const size_t scoreUB = (size_t)B_IMG * NUM_CLASSES * N_ANCH;                   // 32,256,000 (u8)
    const size_t need_new = clsSB + clsBB + topselB + scoreUB;                     // ~36.1 MB

    char* base = (char*)d_ws;

    if (ws_size >= need_new) {
        float* cls_score = (float*)base;
        float* cls_box   = (float*)(base + clsSB);
        unsigned long long* topsel =
            (unsigned long long*)(base + clsSB + clsBB);
        unsigned char* score_u8 =
            (unsigned char*)(base + clsSB + clsBB + topselB);

        decode_score_kernel<<<B_IMG * TILES_PER_IMG, 256, 0, stream>>>(
            p3, p4, p5, score_u8);
        select_topk_u8_kernel<<<B_IMG * NUM_CLASSES, 256, 0, stream>>>(
            score_u8, p3, p4, p5, topsel);
        nms_kernel<<<B_IMG * NUM_CLASSES, 64, 0, stream>>>(
            topsel, p3, p4, p5, cls_score, cls_box);
        final_fast_kernel<<<B_IMG, 256, 0, stream>>>(cls_score, cls_box, (float*)d_out);
    } else {
        float* boxes = (float*)base;
        float* obj = boxes + (size_t)B_IMG * N_ANCH * 4;
        float* cls_score = obj + (size_t)B_IMG * N_ANCH;
        float* cls_box = cls_score + (size_t)B_IMG * NUM_CLASSES * MAX_OUT_;

        int tot = B_IMG * N_ANCH;
        decode_kernel<<<(tot + 255) / 256, 256, 0, stream>>>(p3, p4, p5, boxes, obj);
        topk_nms_kernel<<<B_IMG * NUM_CLASSES, 256, 0, stream>>>(
            p3, p4, p5, boxes, obj, cls_score, cls_box);
        final_fast_kernel<<<B_IMG, 256, 0, stream>>>(cls_score, cls_box, (float*)d_out);
    }
}